// Round 13
// baseline (123.901 us; speedup 1.0000x reference)
//
#include <hip/hip_runtime.h>
#include <math.h>

// Problem constants (B,C,H,W = 8,256,64,64; N = H*W = 4096)
#define BQ 8
#define CQ 256
#define NQ 4096
#define MT 128            // m-tile per block -> 256 blocks, 1/CU
#define NSUP 64           // supersteps (2 chunks of 32n each)

typedef short s16x8 __attribute__((ext_vector_type(8)));
typedef short s16x4 __attribute__((ext_vector_type(4)));
typedef float f32x4 __attribute__((ext_vector_type(4)));
typedef float f32x16 __attribute__((ext_vector_type(16)));
typedef unsigned int uint;

static __device__ __forceinline__ float4 ld4(const float* p) { return *(const float4*)p; }

static constexpr float LOG2E = 1.4426950408889634f;

static __device__ __forceinline__ short f2bf(float f) {
    return __builtin_bit_cast(short, (__bf16)f);
}
// monotonic uint key for float compare via atomicMax/Min
static __device__ __forceinline__ uint fkey(float f) {
    uint b = __builtin_bit_cast(uint, f);
    return b ^ (0x80000000u | (uint)((int)b >> 31));
}
static __device__ __forceinline__ float fdec(uint u) {
    uint b = (u & 0x80000000u) ? (u ^ 0x80000000u) : ~u;
    return __builtin_bit_cast(float, b);
}

// -------- K1: f' = (wq.x)*log2e, g = wk.x, xbf = bf16(x), fused batch max/min --------
__global__ void k_fg(const float* __restrict__ x, const float* __restrict__ wq,
                     const float* __restrict__ wk, float* __restrict__ fs,
                     float* __restrict__ g, short* __restrict__ xbf,
                     uint* __restrict__ fmxu, uint* __restrict__ fmnu) {
    int b = blockIdx.y;
    int t = threadIdx.x;
    int nl = (t & 31) * 2;
    int cg = t >> 5;                     // 0..7
    int n = blockIdx.x * 64 + nl;
    const float* xb = x + (size_t)b * CQ * NQ + n;
    uint* xo = (uint*)(xbf + (size_t)b * CQ * NQ + n);
    float f0 = 0.f, f1 = 0.f, g0 = 0.f, g1 = 0.f;
    int c0 = cg * 32;
#pragma unroll 8
    for (int c = c0; c < c0 + 32; ++c) {
        float2 v = *(const float2*)&xb[(size_t)c * NQ];
        f0 = fmaf(wq[c], v.x, f0);
        f1 = fmaf(wq[c], v.y, f1);
        g0 = fmaf(wk[c], v.x, g0);
        g1 = fmaf(wk[c], v.y, g1);
        uint p = (uint)(unsigned short)f2bf(v.x) | ((uint)(unsigned short)f2bf(v.y) << 16);
        xo[c * (NQ / 2)] = p;
    }
    __shared__ float sf[8][64], sg2[8][64];
    sf[cg][nl] = f0;  sf[cg][nl + 1] = f1;
    sg2[cg][nl] = g0; sg2[cg][nl + 1] = g1;
    __syncthreads();
    if (t < 64) {
        float f = 0.f, gg = 0.f;
#pragma unroll
        for (int i = 0; i < 8; ++i) { f += sf[i][t]; gg += sg2[i][t]; }
        f *= LOG2E;
        fs[b * NQ + blockIdx.x * 64 + t] = f;
        g[b * NQ + blockIdx.x * 64 + t]  = gg;
        float mx = f, mn = f;
#pragma unroll
        for (int off = 32; off; off >>= 1) {
            mx = fmaxf(mx, __shfl_xor(mx, off));
            mn = fminf(mn, __shfl_xor(mn, off));
        }
        if (t == 0) {
            atomicMax(&fmxu[b], fkey(mx));
            atomicMin(&fmnu[b], fkey(mn));
        }
    }
}

// LDS map (bytes):
//   [0, 98304)        : ring, 6 x 16KB chunk slots (256c x 32n bf16, 16B-slot swizzled)
//   [98304, 114688)   : f_lds (4096 f32)
//   [0, 131072)       : post-loop merge overlay (4 ws-pairs x 32KB f32)
//   [131072, 133120)  : zbuf (8 waves x 64 m f32)
//   [0, 65536)        : post-merge y_lds overlay (128m x 512B rows, XOR-swizzled)
#define FLDS_OFF 98304
#define ZBUF_OFF 131072
#define SMEM_BYTES 133120

#define GSRC(p) (const __attribute__((address_space(1))) void*)(p)
#define LDST(p) (__attribute__((address_space(3))) void*)(p)

// 16B-slot swizzle key: period-32 (covers all 32 rows a 32x32 MFMA reads)
#define SWZKEY(row) ((((row) >> 1) & 3) ^ (((row) >> 3) & 3))

// -------- K2 fused: y[c][m] = sum_n x[c][n] e[n,m];  o = (1-gam)*wv*(y/Z) + gam*x --------
// 256 blocks (1/CU) x 512 thr, 8 waves: ws = w&1 (chunk parity), wm = (w>>1)&1
// (m-half), wc = w>>2 (c-half). Wave tile 128c x 64m on mfma_f32_32x32x16_bf16.
// T15 pipeline: MFMA(chunk p, bv precomputed) issues FIRST, then e-gen(chunk p+1)
// runs on VALU/trans while the matrix pipe executes — breaks the serial-sum regime.
// Counted s_waitcnt vmcnt(4) + raw s_barrier (stage pairs p+1/p+2 in flight).
__global__ void __launch_bounds__(512, 2) k_attn(
    const short* __restrict__ xbf, const float* __restrict__ fsp,
    const float* __restrict__ gp, const uint* __restrict__ fmxu,
    const uint* __restrict__ fmnu, const float* __restrict__ wv,
    const float* __restrict__ x, const float* __restrict__ gamma,
    float* __restrict__ out) {
    __shared__ __align__(16) char smem[SMEM_BYTES];

    int bid = blockIdx.x;
    int b = bid & 7;            // batch -> XCD affinity (2MB xbf slice per XCD L2)
    int mblk = bid >> 3;        // 0..31
    int m0 = mblk * MT;
    int tid = threadIdx.x;
    int l = tid & 63;
    int w = tid >> 6;           // 0..7
    int ws = w & 1;             // chunk parity
    int wm = (w >> 1) & 1;      // m-half
    int wc = w >> 2;            // c-half
    int col = l & 31;           // 32x32 A-row / B-col within tile
    int hi = l >> 5;            // k-half selector
    int q = l >> 4;             // 16x16 k-slot (GEMM2)
    int cr = l & 15;            // 16x16 row/col (GEMM2)

    const short* xb = xbf + (size_t)b * CQ * NQ;
    const float* fb = fsp + b * NQ;

    // stage addressing: 512 thr x 16B x 2 issues = one 16KB chunk.
    // Linear LDS dest; swizzle pre-applied on GLOBAL source (both-sides involution).
    int dst = tid * 16;
    int srow0 = tid >> 2;                 // rows 0..127
    int srow1 = srow0 + 128;              // rows 128..255
    const short* src0 = xb + (size_t)srow0 * NQ + ((tid & 3) ^ SWZKEY(srow0)) * 8;
    const short* src1 = xb + (size_t)srow1 * NQ + ((tid & 3) ^ SWZKEY(srow1)) * 8;

    // ---- prologue: stage f (2 loads) + chunks 0..3 (8 loads) ----
    __builtin_amdgcn_global_load_lds(GSRC(fb + tid * 4),
        LDST(smem + FLDS_OFF + dst), 16, 0, 0);
    __builtin_amdgcn_global_load_lds(GSRC(fb + tid * 4 + 2048),
        LDST(smem + FLDS_OFF + 8192 + dst), 16, 0, 0);
#pragma unroll
    for (int k = 0; k < 4; ++k) {
        __builtin_amdgcn_global_load_lds(GSRC(src0 + k * 32),
            LDST(smem + k * 16384 + dst), 16, 0, 0);
        __builtin_amdgcn_global_load_lds(GSRC(src1 + k * 32),
            LDST(smem + k * 16384 + 8192 + dst), 16, 0, 0);
    }

    float fmx = fdec(fmxu[b]), fmn = fdec(fmnu[b]);
    const float* gb = gp + b * NQ;
    float gj[2], nM[2], zac[2] = {0.f, 0.f};
#pragma unroll
    for (int mt = 0; mt < 2; ++mt) {
        float gv = gb[m0 + wm * 64 + mt * 32 + col];
        gj[mt] = gv;
        nM[mt] = -((gv >= 0.f) ? gv * fmx : gv * fmn);
    }

    // A-read addressing: row = wc*128 + ct*32 + col
    int rowoff[4], rkey[4];
#pragma unroll
    for (int ct = 0; ct < 4; ++ct) {
        int row = wc * 128 + ct * 32 + col;
        rowoff[ct] = row * 64;
        rkey[ct] = SWZKEY(row) * 16;
    }

    f32x16 acc[4][2];
#pragma unroll
    for (int ct = 0; ct < 4; ++ct)
#pragma unroll
        for (int mt = 0; mt < 2; ++mt)
#pragma unroll
            for (int r = 0; r < 16; ++r) acc[ct][mt][r] = 0.f;

    // f landed (oldest 2 of 10)
    asm volatile("s_waitcnt vmcnt(8)" ::: "memory");
    __builtin_amdgcn_s_barrier();
    const float* fl0 = (const float*)(smem + FLDS_OFF);

    // bv double-buffer: bvb[parity][mt][kt]; prologue fills parity 0 (chunk ws)
    s16x8 bvb[2][2][2];
    float4 fc[4];
    {
        int n0 = ws * 32;
        fc[0] = *(const float4*)(fl0 + n0 + 8 * hi);
        fc[1] = *(const float4*)(fl0 + n0 + 8 * hi + 4);
        fc[2] = *(const float4*)(fl0 + n0 + 16 + 8 * hi);
        fc[3] = *(const float4*)(fl0 + n0 + 16 + 8 * hi + 4);
    }
#pragma unroll
    for (int kt = 0; kt < 2; ++kt) {
        float fq[8] = {fc[kt*2].x, fc[kt*2].y, fc[kt*2].z, fc[kt*2].w,
                       fc[kt*2+1].x, fc[kt*2+1].y, fc[kt*2+1].z, fc[kt*2+1].w};
#pragma unroll
        for (int mt = 0; mt < 2; ++mt) {
            float z = zac[mt];
#pragma unroll
            for (int i = 0; i < 8; ++i) {
                float e = __builtin_amdgcn_exp2f(fmaf(fq[i], gj[mt], nM[mt]));
                z += e;
                bvb[0][mt][kt][i] = f2bf(e);
            }
            zac[mt] = z;
        }
    }
    {   // fc <- f(chunk 2+ws) for iter 0's e-gen
        int nn = (2 + ws) * 32;
        fc[0] = *(const float4*)(fl0 + nn + 8 * hi);
        fc[1] = *(const float4*)(fl0 + nn + 8 * hi + 4);
        fc[2] = *(const float4*)(fl0 + nn + 16 + 8 * hi);
        fc[3] = *(const float4*)(fl0 + nn + 16 + 8 * hi + 4);
    }

    int rs = 0;    // ring slot of chunk 2p
    int ssl = 4;   // ring slot target for chunk 2p+4
#pragma unroll 2
    for (int p = 0; p < NSUP; ++p) {
        // pair p landed; pair p+1 (4 loads) stays in flight across the barrier
        asm volatile("s_waitcnt vmcnt(4)" ::: "memory");
        __builtin_amdgcn_s_barrier();
        // stage pair p+2 (wrapped at tail for uniform vmcnt; slots never re-read)
        {
            int chA = (2 * p + 4) & 127;
            __builtin_amdgcn_global_load_lds(GSRC(src0 + chA * 32),
                LDST(smem + ssl * 16384 + dst), 16, 0, 0);
            __builtin_amdgcn_global_load_lds(GSRC(src1 + chA * 32),
                LDST(smem + ssl * 16384 + 8192 + dst), 16, 0, 0);
            __builtin_amdgcn_global_load_lds(GSRC(src0 + chA * 32 + 32),
                LDST(smem + (ssl + 1) * 16384 + dst), 16, 0, 0);
            __builtin_amdgcn_global_load_lds(GSRC(src1 + chA * 32 + 32),
                LDST(smem + (ssl + 1) * 16384 + 8192 + dst), 16, 0, 0);
        }
        // ---- MFMA cluster FIRST: chunk 2p+ws, bv precomputed last superstep ----
        const char* cbuf = smem + (rs + ws) * 16384;
#pragma unroll
        for (int kt = 0; kt < 2; ++kt) {
            int lslot = (kt * 2 + hi) * 16;
#pragma unroll
            for (int ct = 0; ct < 4; ++ct) {
                s16x8 av = *(const s16x8*)(cbuf + rowoff[ct] + (lslot ^ rkey[ct]));
                acc[ct][0] = __builtin_amdgcn_mfma_f32_32x32x16_bf16(av, bvb[p & 1][0][kt], acc[ct][0], 0, 0, 0);
                acc[ct][1] = __builtin_amdgcn_mfma_f32_32x32x16_bf16(av, bvb[p & 1][1][kt], acc[ct][1], 0, 0, 0);
            }
        }
        // ---- e-gen for chunk 2(p+1)+ws: VALU/trans overlaps the matrix pipe ----
        if (p + 1 < NSUP) {
#pragma unroll
            for (int kt = 0; kt < 2; ++kt) {
                float fq[8] = {fc[kt*2].x, fc[kt*2].y, fc[kt*2].z, fc[kt*2].w,
                               fc[kt*2+1].x, fc[kt*2+1].y, fc[kt*2+1].z, fc[kt*2+1].w};
#pragma unroll
                for (int mt = 0; mt < 2; ++mt) {
                    float z = zac[mt];
#pragma unroll
                    for (int i = 0; i < 8; ++i) {
                        float e = __builtin_amdgcn_exp2f(fmaf(fq[i], gj[mt], nM[mt]));
                        z += e;
                        bvb[(p + 1) & 1][mt][kt][i] = f2bf(e);
                    }
                    zac[mt] = z;
                }
            }
            // fc <- f(chunk 2(p+2)+ws)
            int nn = ((2 * p + 4 + ws) & 127) * 32;
            fc[0] = *(const float4*)(fl0 + nn + 8 * hi);
            fc[1] = *(const float4*)(fl0 + nn + 8 * hi + 4);
            fc[2] = *(const float4*)(fl0 + nn + 16 + 8 * hi);
            fc[3] = *(const float4*)(fl0 + nn + 16 + 8 * hi + 4);
        }
        rs += 2;  if (rs >= 6) rs -= 6;
        ssl += 2; if (ssl >= 6) ssl -= 6;
    }
    __syncthreads();   // full drain (incl. wrap stages) before overlays

    // ---- Z finalize: lane + partner (hi) hold complementary k-halves ----
    float zf[2];
#pragma unroll
    for (int mt = 0; mt < 2; ++mt) {
        float z = zac[mt];
        z += __shfl_xor(z, 32);
        zf[mt] = z;
    }
    {
        float* zb = (float*)(smem + ZBUF_OFF);
        if (l < 32) {
#pragma unroll
            for (int mt = 0; mt < 2; ++mt) zb[w * 64 + mt * 32 + l] = zf[mt];
        }
        // ---- acc merge across ws pairs: ws1 -> LDS (f32, 4 x 32KB), ws0 adds ----
        int p8 = wc * 2 + wm;
        float* mrg = (float*)(smem + p8 * 32768);
        if (ws == 1) {
#pragma unroll
            for (int ct = 0; ct < 4; ++ct)
#pragma unroll
                for (int mt = 0; mt < 2; ++mt) {
                    int fi = ct * 2 + mt;
#pragma unroll
                    for (int j = 0; j < 4; ++j) {
                        f32x4 v = {acc[ct][mt][4*j], acc[ct][mt][4*j+1],
                                   acc[ct][mt][4*j+2], acc[ct][mt][4*j+3]};
                        *(f32x4*)(mrg + ((fi * 4 + j) * 64 + l) * 4) = v;
                    }
                }
        }
        __syncthreads();
        if (ws == 0) {
#pragma unroll
            for (int ct = 0; ct < 4; ++ct)
#pragma unroll
                for (int mt = 0; mt < 2; ++mt) {
                    int fi = ct * 2 + mt;
#pragma unroll
                    for (int j = 0; j < 4; ++j) {
                        f32x4 o = *(const f32x4*)(mrg + ((fi * 4 + j) * 64 + l) * 4);
#pragma unroll
                        for (int i = 0; i < 4; ++i) acc[ct][mt][4*j+i] += o[i];
                    }
                }
        }
#pragma unroll
        for (int mt = 0; mt < 2; ++mt) zf[mt] += zb[(w ^ 1) * 64 + mt * 32 + col];
        __syncthreads();   // merge reads done before y_lds overwrites region
    }

    // ---- y_norm -> LDS (ws0): y_lds[m][c] bf16, 512B rows, XOR-swizzled ----
    // 32x32 C/D: col = l&31, row = (reg&3) + 8*(reg>>2) + 4*hi
    if (ws == 0) {
        float rzl[2] = {1.0f / zf[0], 1.0f / zf[1]};
#pragma unroll
        for (int ct = 0; ct < 4; ++ct)
#pragma unroll
            for (int mt = 0; mt < 2; ++mt) {
                int mloc = wm * 64 + mt * 32 + col;
                int key = (mloc & 7) << 4;
#pragma unroll
                for (int j = 0; j < 4; ++j) {
                    int cb = (wc * 256 + ct * 64 + 16 * j + 8 * hi) ^ key;
                    s16x4 v;
#pragma unroll
                    for (int i = 0; i < 4; ++i) v[i] = f2bf(acc[ct][mt][4*j+i] * rzl[mt]);
                    *(s16x4*)(smem + mloc * 512 + cb) = v;
                }
            }
    }
    __syncthreads();

    // ---- GEMM2: o[c_out][m] = wv[c_out][:] . y_norm[:][m], K=256 (8 waves, 16x16) ----
    int co0 = w * 32;
    f32x4 acc2[2][8];
#pragma unroll
    for (int j2 = 0; j2 < 2; ++j2)
#pragma unroll
        for (int jm2 = 0; jm2 < 8; ++jm2) acc2[j2][jm2] = (f32x4){0.f, 0.f, 0.f, 0.f};

#pragma unroll 2
    for (int ks = 0; ks < 8; ++ks) {
        s16x8 a2[2];
#pragma unroll
        for (int j2 = 0; j2 < 2; ++j2) {
            const float* wr = wv + (size_t)(co0 + j2 * 16 + cr) * CQ + ks * 32 + q * 8;
            float4 wa = ld4(wr);
            float4 wb = ld4(wr + 4);
            a2[j2][0] = f2bf(wa.x); a2[j2][1] = f2bf(wa.y);
            a2[j2][2] = f2bf(wa.z); a2[j2][3] = f2bf(wa.w);
            a2[j2][4] = f2bf(wb.x); a2[j2][5] = f2bf(wb.y);
            a2[j2][6] = f2bf(wb.z); a2[j2][7] = f2bf(wb.w);
        }
#pragma unroll
        for (int jm2 = 0; jm2 < 8; ++jm2) {
            int mloc = jm2 * 16 + cr;
            s16x8 b2 = *(const s16x8*)(smem + mloc * 512 + ((ks * 64 + q * 16) ^ ((mloc & 7) << 4)));
#pragma unroll
            for (int j2 = 0; j2 < 2; ++j2)
                acc2[j2][jm2] = __builtin_amdgcn_mfma_f32_16x16x32_bf16(a2[j2], b2, acc2[j2][jm2], 0, 0, 0);
        }
    }

    // ---- epilogue ----
    float gam = gamma[0];
    float omg = 1.f - gam;
    if (gam != 0.f) {
#pragma unroll
        for (int j2 = 0; j2 < 2; ++j2)
#pragma unroll
            for (int jm2 = 0; jm2 < 8; ++jm2)
#pragma unroll
                for (int r = 0; r < 4; ++r) {
                    int c_out = co0 + j2 * 16 + q * 4 + r;
                    size_t idx = ((size_t)b * CQ + c_out) * NQ + m0 + jm2 * 16 + cr;
                    __builtin_nontemporal_store(
                        fmaf(gam, x[idx], acc2[j2][jm2][r] * omg), out + idx);
                }
    } else {
#pragma unroll
        for (int j2 = 0; j2 < 2; ++j2)
#pragma unroll
            for (int jm2 = 0; jm2 < 8; ++jm2)
#pragma unroll
                for (int r = 0; r < 4; ++r) {
                    int c_out = co0 + j2 * 16 + q * 4 + r;
                    size_t idx = ((size_t)b * CQ + c_out) * NQ + m0 + jm2 * 16 + cr;
                    __builtin_nontemporal_store(acc2[j2][jm2][r] * omg, out + idx);
                }
    }
}

extern "C" void kernel_launch(void* const* d_in, const int* in_sizes, int n_in,
                              void* d_out, int out_size, void* d_ws, size_t ws_size,
                              hipStream_t stream) {
    const float* x     = (const float*)d_in[0];
    const float* wq    = (const float*)d_in[1];
    const float* wk    = (const float*)d_in[2];
    const float* wv    = (const float*)d_in[3];
    const float* gamma = (const float*)d_in[4];
    float* out = (float*)d_out;

    // ws (floats): fs[B*N] | g[B*N] | fmxu[8]+fmnu[8] (uint) | pad -> xbf (bf16) [B*C*N]
    float* ws  = (float*)d_ws;
    float* fs  = ws;
    float* g   = ws + BQ * NQ;
    uint* fmxu = (uint*)(ws + 2 * BQ * NQ);
    uint* fmnu = fmxu + 8;
    short* xbf = (short*)(ws + 2 * BQ * NQ + 64);

    hipMemsetAsync(fmxu, 0x00, 32, stream);   // lowest key
    hipMemsetAsync(fmnu, 0xFF, 32, stream);   // highest key
    hipLaunchKernelGGL(k_fg, dim3(NQ / 64, BQ), dim3(256), 0, stream,
                       x, wq, wk, fs, g, xbf, fmxu, fmnu);
    hipLaunchKernelGGL(k_attn, dim3(BQ * (NQ / MT)), dim3(512), 0, stream,
                       xbf, fs, g, fmxu, fmnu, wv, x, gamma, out);
}